// Round 1
// baseline (386986.108 us; speedup 1.0000x reference)
//
#include <hip/hip_runtime.h>
#include <math.h>

// Problem constants (BottomLevelDecoderRNN): B=256, BARS=16, CH=512, H=1024, V=130, T=256
#define B_    256
#define BARS_ 16
#define CH_   512
#define H_    1024
#define V_    130
#define T_    256
#define G4_   4096            // 4*H
#define BH_   (B_ * H_)       // 262144
#define BG_   ((long)B_ * G4_) // 1048576

// ---------------------------------------------------------------------------
// Generic fused fp32 gemm:  C = act( A0@W0^T [+ A1@W1^T] + base0[gather] + base1 + base2 + bias )
// A: (M x K) row-major lda; W: (N x K) row-major ldw; bases: (M x N) ld = N.
// Per-z pointer strides allow batching independent gemms in gridDim.z.
// ---------------------------------------------------------------------------
struct GemmP {
  const float* A0; int lda0; long a0z;
  const float* A0b;                    // optional elementwise-add second A (same lda0/a0z)
  const float* W0; int ldw0; long w0z; int K0;
  const float* A1; int lda1; long a1z; // optional second pair
  const float* W1; int ldw1; long w1z; int K1;
  const float* base0; long b0z;
  const int*   gidx; int gstride; long gz; // optional row-gather for base0
  const float* base1; long b1z;
  const float* base2; long b2z;
  const float* bias;  long biasz;
  float* C; int ldc; long cz;
  int M, N, act;                       // act: 0=none, 1=tanh
};

__global__ __launch_bounds__(256) void gemm_f32(GemmP p) {
  __shared__ float As[16][65];
  __shared__ float Ws[16][65];
  const int z  = blockIdx.z;
  const int m0 = blockIdx.y * 64;
  const int n0 = blockIdx.x * 64;
  const int tid = threadIdx.x;
  const int lr = tid >> 2;          // 0..63 : row of A-tile / n of W-tile to load
  const int lk = (tid & 3) * 4;     // k offset (float4)
  const int tm = tid >> 4;          // 0..15
  const int tn = tid & 15;          // 0..15

  float acc[4][4];
#pragma unroll
  for (int j = 0; j < 4; ++j)
#pragma unroll
    for (int i = 0; i < 4; ++i) acc[j][i] = 0.f;

  for (int pair = 0; pair < 2; ++pair) {
    if (pair == 1 && p.A1 == nullptr) break;
    const float* A  = pair ? p.A1 + (long)z * p.a1z : p.A0 + (long)z * p.a0z;
    const float* Ab = (pair == 0 && p.A0b) ? p.A0b + (long)z * p.a0z : nullptr;
    const float* W  = pair ? p.W1 + (long)z * p.w1z : p.W0 + (long)z * p.w0z;
    const int lda = pair ? p.lda1 : p.lda0;
    const int ldw = pair ? p.ldw1 : p.ldw0;
    const int K   = pair ? p.K1   : p.K0;

    for (int k0 = 0; k0 < K; k0 += 16) {
      float4 av = make_float4(0.f, 0.f, 0.f, 0.f);
      const int ar = m0 + lr;
      if (ar < p.M) {
        av = *(const float4*)(A + (long)ar * lda + k0 + lk);
        if (Ab) {
          float4 t = *(const float4*)(Ab + (long)ar * lda + k0 + lk);
          av.x += t.x; av.y += t.y; av.z += t.z; av.w += t.w;
        }
      }
      float4 wv = make_float4(0.f, 0.f, 0.f, 0.f);
      const int wr = n0 + lr;
      if (wr < p.N) wv = *(const float4*)(W + (long)wr * ldw + k0 + lk);

      __syncthreads();
      As[lk + 0][lr] = av.x; As[lk + 1][lr] = av.y; As[lk + 2][lr] = av.z; As[lk + 3][lr] = av.w;
      Ws[lk + 0][lr] = wv.x; Ws[lk + 1][lr] = wv.y; Ws[lk + 2][lr] = wv.z; Ws[lk + 3][lr] = wv.w;
      __syncthreads();

#pragma unroll
      for (int kk = 0; kk < 16; ++kk) {
        float a[4], b[4];
#pragma unroll
        for (int j = 0; j < 4; ++j) a[j] = As[kk][tm * 4 + j];
#pragma unroll
        for (int i = 0; i < 4; ++i) b[i] = Ws[kk][tn * 4 + i];
#pragma unroll
        for (int j = 0; j < 4; ++j)
#pragma unroll
          for (int i = 0; i < 4; ++i) acc[j][i] += a[j] * b[i];
      }
    }
  }

  const float* base0 = p.base0 ? p.base0 + (long)z * p.b0z : nullptr;
  const float* base1 = p.base1 ? p.base1 + (long)z * p.b1z : nullptr;
  const float* base2 = p.base2 ? p.base2 + (long)z * p.b2z : nullptr;
  const float* bias  = p.bias  ? p.bias  + (long)z * p.biasz : nullptr;
  const int*   gidx  = p.gidx  ? p.gidx  + (long)z * p.gz : nullptr;
  float* C = p.C + (long)z * p.cz;

#pragma unroll
  for (int j = 0; j < 4; ++j) {
    const int row = m0 + tm * 4 + j;
    if (row >= p.M) continue;
    long b0row = row;
    if (gidx) b0row = gidx[(long)row * p.gstride];
#pragma unroll
    for (int i = 0; i < 4; ++i) {
      const int col = n0 + tn * 4 + i;
      if (col >= p.N) continue;
      float v = acc[j][i];
      if (base0) v += base0[b0row * (long)p.N + col];
      if (base1) v += base1[(long)row * p.N + col];
      if (base2) v += base2[(long)row * p.N + col];
      if (bias)  v += bias[col];
      if (p.act == 1) v = tanhf(v);
      C[(long)row * p.ldc + col] = v;
    }
  }
}

// h = sigmoid(o) * tanh( sigmoid(i) * tanh(g) );  gates layout: [i | f | g | o] each H wide
__global__ __launch_bounds__(256) void lstm_act_k(const float* g, long gz, float* h, long hz) {
  const int z = blockIdx.y;
  const long idx = (long)blockIdx.x * 256 + threadIdx.x; // < B*H
  const int b = (int)(idx >> 10);
  const int j = (int)(idx & 1023);
  const float* gr = g + z * gz + (long)b * G4_;
  const float vi = gr[j];
  const float vg = gr[2 * H_ + j];
  const float vo = gr[3 * H_ + j];
  const float si = 1.f / (1.f + expf(-vi));
  const float so = 1.f / (1.f + expf(-vo));
  h[z * hz + idx] = so * tanhf(si * tanhf(vg));
}

// bar reset: h1[0..2] = h2[0..2] = ctx = Hbar
__global__ __launch_bounds__(256) void reset_k(const float* Hbar, float* h1, float* h2, float* ctx) {
  const long idx = (long)blockIdx.x * 256 + threadIdx.x;
  const float v = Hbar[idx];
  h1[idx] = v; h1[idx + BH_] = v; h1[idx + 2L * BH_] = v;
  h2[idx] = v; h2[idx + BH_] = v; h2[idx + 2L * BH_] = v;
  ctx[idx] = v;
}

// x1cat[i][b][k] = k<CH ? emb[i][0][k] : c[b][bar][k-CH]
__global__ __launch_bounds__(256) void x1cat_k(const float* emb, const float* c, int bar, float* x1) {
  const long idx = (long)blockIdx.x * 256 + threadIdx.x; // < 3*B*1024
  const int i = (int)(idx >> 18);
  const int r = (int)(idx & 262143);
  const int b = r >> 10;
  const int k = r & 1023;
  float v;
  if (k < CH_) v = emb[(long)i * V_ * CH_ + k];
  else         v = c[(long)b * BARS_ * CH_ + (long)bar * CH_ + (k - CH_)];
  x1[idx] = v;
}

static inline void launch_gemm(const GemmP& p, int Z, hipStream_t s) {
  dim3 grid((p.N + 63) / 64, (p.M + 63) / 64, Z);
  hipLaunchKernelGGL(gemm_f32, grid, dim3(256), 0, s, p);
}

extern "C" void kernel_launch(void* const* d_in, const int* in_sizes, int n_in,
                              void* d_out, int out_size, void* d_ws, size_t ws_size,
                              hipStream_t stream) {
  const float* c     = (const float*)d_in[0];
  const float* l1Wih = (const float*)d_in[1];  // (3, 4096, 1024)
  const float* l1Whh = (const float*)d_in[2];  // (3, 4096, 1024)
  const float* l1b   = (const float*)d_in[3];  // (3, 4096)
  const float* cWih  = (const float*)d_in[4];  // (4096, 3072)
  const float* cWhh  = (const float*)d_in[5];  // (4096, 1024)
  const float* cb    = (const float*)d_in[6];  // (4096)
  const float* l2Wih = (const float*)d_in[7];  // (3, 4096, 1536)
  const float* l2Whh = (const float*)d_in[8];  // (3, 4096, 1024)
  const float* l2b   = (const float*)d_in[9];  // (3, 4096)
  const float* outW  = (const float*)d_in[10]; // (3, 130, 1024)
  const float* outb  = (const float*)d_in[11]; // (3, 130)
  const float* hidW  = (const float*)d_in[12]; // (1024, 512)
  const float* hidb  = (const float*)d_in[13]; // (1024)
  const float* emb   = (const float*)d_in[14]; // (3, 130, 512)
  const int*   target= (const int*)d_in[15];   // (3, 256, 256)
  float* out = (float*)d_out;                  // 3 x (B, T, V) concatenated

  // workspace carve (floats); total ~24.93M floats ~= 99.7 MB
  float* w = (float*)d_ws;
  float* embW  = w; w += 3L * V_ * G4_;
  float* x1cat = w; w += 3L * B_ * (2 * CH_);
  float* xW1   = w; w += 3L * BG_;
  float* cW2   = w; w += 3L * BG_;
  float* cWu   = w; w += 1L * BG_;
  float* Hbar  = w; w += 1L * BH_;
  float* h1    = w; w += 3L * BH_;
  float* h2    = w; w += 3L * BH_;
  float* ctxb  = w; w += 1L * BH_;
  float* unew  = w; w += 2L * BH_;
  float* Pb    = w; w += 3L * BG_;
  float* Pp    = w; w += 2L * BG_;
  float* g1    = w; w += 3L * BG_;
  float* gu    = w; w += 2L * BG_;
  float* gc    = w; w += 1L * BG_;
  float* gh2   = w; w += 1L * BG_;

  // --- once: embW[i][v] = emb[i][v] @ lstm1_Wih[1][:, :512]^T   (no bias; bias folded into cWu)
  {
    GemmP p{}; p.A0 = emb; p.lda0 = CH_; p.a0z = (long)V_ * CH_;
    p.W0 = l1Wih + (long)G4_ * (2 * CH_); p.ldw0 = 2 * CH_; p.w0z = 0; p.K0 = CH_;
    p.C = embW; p.ldc = G4_; p.cz = (long)V_ * G4_; p.M = V_; p.N = G4_;
    launch_gemm(p, 3, stream);
  }

  for (int t = 0; t < T_; ++t) {
    const int bar = t >> 4;
    if ((t & 15) == 0) {
      const int prev = bar ? bar - 1 : 0;
      { // Hbar = tanh(c[:,prev,:] @ hid_W^T + hid_b)
        GemmP p{}; p.A0 = c + (long)prev * CH_; p.lda0 = BARS_ * CH_;
        p.W0 = hidW; p.ldw0 = CH_; p.K0 = CH_;
        p.bias = hidb;
        p.C = Hbar; p.ldc = H_; p.M = B_; p.N = H_; p.act = 1;
        launch_gemm(p, 1, stream);
      }
      hipLaunchKernelGGL(reset_k, dim3(BH_ / 256), dim3(256), 0, stream, Hbar, h1, h2, ctxb);
      hipLaunchKernelGGL(x1cat_k, dim3(3 * BH_ / 256), dim3(256), 0, stream, emb, c, bar, x1cat);
      { // xW1[i] = x1cat[i] @ lstm1_Wih[i]^T + lstm1_b[i]
        GemmP p{}; p.A0 = x1cat; p.lda0 = 2 * CH_; p.a0z = (long)B_ * (2 * CH_);
        p.W0 = l1Wih; p.ldw0 = 2 * CH_; p.w0z = (long)G4_ * (2 * CH_); p.K0 = 2 * CH_;
        p.bias = l1b; p.biasz = G4_;
        p.C = xW1; p.ldc = G4_; p.cz = BG_; p.M = B_; p.N = G4_;
        launch_gemm(p, 3, stream);
      }
      { // cW2[i] = c_bar @ lstm2_Wih[i][:, 1024:]^T + lstm2_b[i]
        GemmP p{}; p.A0 = c + (long)bar * CH_; p.lda0 = BARS_ * CH_; p.a0z = 0;
        p.W0 = l2Wih + H_; p.ldw0 = H_ + CH_; p.w0z = (long)G4_ * (H_ + CH_); p.K0 = CH_;
        p.bias = l2b; p.biasz = G4_;
        p.C = cW2; p.ldc = G4_; p.cz = BG_; p.M = B_; p.N = G4_;
        launch_gemm(p, 3, stream);
      }
      { // cWu = c_bar @ lstm1_Wih[1][:, 512:]^T + lstm1_b[1]
        GemmP p{}; p.A0 = c + (long)bar * CH_; p.lda0 = BARS_ * CH_;
        p.W0 = l1Wih + (long)G4_ * (2 * CH_) + CH_; p.ldw0 = 2 * CH_; p.K0 = CH_;
        p.bias = l1b + G4_;
        p.C = cWu; p.ldc = G4_; p.M = B_; p.N = G4_;
        launch_gemm(p, 1, stream);
      }
    }

    { // g1[i] = xW1[i] + h1[i] @ lstm1_Whh[i]^T
      GemmP p{}; p.A0 = h1; p.lda0 = H_; p.a0z = BH_;
      p.W0 = l1Whh; p.ldw0 = H_; p.w0z = (long)G4_ * H_; p.K0 = H_;
      p.base0 = xW1; p.b0z = BG_;
      p.C = g1; p.ldc = G4_; p.cz = BG_; p.M = B_; p.N = G4_;
      launch_gemm(p, 3, stream);
    }
    hipLaunchKernelGGL(lstm_act_k, dim3(BH_ / 256, 3), dim3(256), 0, stream, g1, BG_, h1, (long)BH_);

    { // gu[i] = embW[i][tg] + cWu + h1[i] @ lstm1_Whh[1]^T   (i = 0,1 only; i=2 update is dead)
      GemmP p{}; p.A0 = h1; p.lda0 = H_; p.a0z = BH_;
      p.W0 = l1Whh + (long)G4_ * H_; p.ldw0 = H_; p.w0z = 0; p.K0 = H_;
      p.base0 = embW; p.b0z = (long)V_ * G4_;
      p.gidx = target + t; p.gstride = T_; p.gz = (long)B_ * T_;
      p.base1 = cWu; p.b1z = 0;
      p.C = gu; p.ldc = G4_; p.cz = BG_; p.M = B_; p.N = G4_;
      launch_gemm(p, 2, stream);
    }
    hipLaunchKernelGGL(lstm_act_k, dim3(BH_ / 256, 2), dim3(256), 0, stream, gu, BG_, unew, (long)BH_);

    { // P[j] = h1[j] @ ctx_Wih[:, j*1024:(j+1)*1024]^T
      GemmP p{}; p.A0 = h1; p.lda0 = H_; p.a0z = BH_;
      p.W0 = cWih; p.ldw0 = 3 * H_; p.w0z = H_; p.K0 = H_;
      p.C = Pb; p.ldc = G4_; p.cz = BG_; p.M = B_; p.N = G4_;
      launch_gemm(p, 3, stream);
    }
    { // Pp[j] = unew[j] @ ctx_Wih[:, j*1024:(j+1)*1024]^T  (j = 0,1)
      GemmP p{}; p.A0 = unew; p.lda0 = H_; p.a0z = BH_;
      p.W0 = cWih; p.ldw0 = 3 * H_; p.w0z = H_; p.K0 = H_;
      p.C = Pp; p.ldc = G4_; p.cz = BG_; p.M = B_; p.N = G4_;
      launch_gemm(p, 2, stream);
    }

    for (int i = 0; i < 3; ++i) {
      const float* b0 = (i >= 1) ? Pp       : Pb;
      const float* b1 = (i >= 2) ? Pp + BG_ : Pb + BG_;
      const float* b2 = Pb + 2 * BG_;
      { // gc = P0 + P1 + P2 + ctx_b + ctx @ ctx_Whh^T
        GemmP p{}; p.A0 = ctxb; p.lda0 = H_;
        p.W0 = cWhh; p.ldw0 = H_; p.K0 = H_;
        p.base0 = b0; p.base1 = b1; p.base2 = b2;
        p.bias = cb;
        p.C = gc; p.ldc = G4_; p.M = B_; p.N = G4_;
        launch_gemm(p, 1, stream);
      }
      hipLaunchKernelGGL(lstm_act_k, dim3(BH_ / 256, 1), dim3(256), 0, stream, gc, 0L, ctxb, 0L);
      { // gh2 = cW2[i] + ctx @ lstm2_Wih[i][:, :1024]^T + h2[i] @ lstm2_Whh[i]^T
        GemmP p{}; p.A0 = ctxb; p.lda0 = H_;
        p.W0 = l2Wih + (long)i * G4_ * (H_ + CH_); p.ldw0 = H_ + CH_; p.K0 = H_;
        p.A1 = h2 + (long)i * BH_; p.lda1 = H_;
        p.W1 = l2Whh + (long)i * G4_ * H_; p.ldw1 = H_; p.K1 = H_;
        p.base0 = cW2 + (long)i * BG_;
        p.C = gh2; p.ldc = G4_; p.M = B_; p.N = G4_;
        launch_gemm(p, 1, stream);
      }
      hipLaunchKernelGGL(lstm_act_k, dim3(BH_ / 256, 1), dim3(256), 0, stream,
                         gh2, 0L, h2 + (long)i * BH_, 0L);
      { // out[i][:, t, :] = (h1[i] + h2[i]) @ out_W[i]^T + out_b[i]
        GemmP p{}; p.A0 = h1 + (long)i * BH_; p.lda0 = H_; p.A0b = h2 + (long)i * BH_;
        p.W0 = outW + (long)i * V_ * H_; p.ldw0 = H_; p.K0 = H_;
        p.bias = outb + (long)i * V_;
        p.C = out + (long)i * B_ * T_ * V_ + (long)t * V_; p.ldc = T_ * V_;
        p.M = B_; p.N = V_;
        launch_gemm(p, 1, stream);
      }
    }
  }
}

// Round 2
// 103239.343 us; speedup vs baseline: 3.7484x; 3.7484x over previous
//
#include <hip/hip_runtime.h>
#include <hip/hip_bf16.h>
#include <math.h>

// BottomLevelDecoderRNN: B=256, BARS=16, CH=512, H=1024, V=130, T=256
#define B_    256
#define BARS_ 16
#define CH_   512
#define H_    1024
#define V_    130
#define T_    256
#define G4_   4096
#define BH_   (B_ * H_)        // 262144
#define BG_   (B_ * G4_)       // 1048576

typedef __hip_bfloat16 bf16;
typedef short s16x8 __attribute__((ext_vector_type(8)));
typedef float f32x4 __attribute__((ext_vector_type(4)));

#define MAXZ 5

// Fused bf16-MFMA gemm: C[g] = A0@W0[gateOff[g]]^T (+ A1@W1^T) + bases + bias
// NG = gates per block (3: i/g/o rows of a 4xH weight; 1: plain)
// MODE 0: store fp32 (+bias); MODE 1: LSTM act -> bf16 h; MODE 2: tanh -> bf16
struct MP {
  const bf16* A0[MAXZ]; const bf16* A0b[MAXZ];
  const bf16* W0[MAXZ];
  const bf16* A1[MAXZ]; const bf16* W1[MAXZ];
  const float* base0[MAXZ]; const int* gidx[MAXZ];
  const float* base1[MAXZ]; const float* base2[MAXZ];
  const float* bias[MAXZ];
  float* Cf[MAXZ]; bf16* Ch[MAXZ];
  int lda0, lda1, ldw0, ldw1, K0, K1;
  int gateOff[3];
  int M, Nc, ldc, ldh, gstride;
};

__device__ __forceinline__ float sigf(float x) { return 1.f / (1.f + __expf(-x)); }
__device__ __forceinline__ float tanhfa(float x) { return 2.f / (1.f + __expf(-2.f * x)) - 1.f; }

template<int NG, int MODE>
__global__ __launch_bounds__(256) void mfma_gemm(MP p) {
  __shared__ bf16 As[64][72];          // +8 pad: 2-way LDS aliasing only (free)
  __shared__ bf16 Ws[NG][64][72];
  const int z   = blockIdx.z;
  const int m0  = blockIdx.y * 64;
  const int n0  = blockIdx.x * 64;
  const int tid = threadIdx.x;
  const int lane = tid & 63;
  const int wv   = tid >> 6;
  const int srow = tid >> 2;           // staging row 0..63
  const int scol = (tid & 3) << 4;     // staging col 0/16/32/48 (16 bf16 per thread)

  f32x4 acc[NG][4];
#pragma unroll
  for (int g = 0; g < NG; ++g)
#pragma unroll
    for (int mf = 0; mf < 4; ++mf) acc[g][mf] = (f32x4){0.f, 0.f, 0.f, 0.f};

  for (int pair = 0; pair < 2; ++pair) {
    const bf16 *A, *Ab = nullptr, *W; int lda, ldw, K;
    if (pair == 0) { A = p.A0[z]; Ab = p.A0b[z]; W = p.W0[z]; lda = p.lda0; ldw = p.ldw0; K = p.K0; }
    else           { A = p.A1[z]; if (!A) break;  W = p.W1[z]; lda = p.lda1; ldw = p.ldw1; K = p.K1; }

    for (int k0 = 0; k0 < K; k0 += 64) {
      bf16 areg[16];
      const int ar = m0 + srow;
      if (ar < p.M) {
        const bf16* ap = A + (long)ar * lda + k0 + scol;
        *(float4*)(areg)     = *(const float4*)(ap);
        *(float4*)(areg + 8) = *(const float4*)(ap + 8);
        if (Ab) {
          const bf16* bp = Ab + (long)ar * lda + k0 + scol;
          bf16 breg[16];
          *(float4*)(breg)     = *(const float4*)(bp);
          *(float4*)(breg + 8) = *(const float4*)(bp + 8);
#pragma unroll
          for (int q = 0; q < 16; ++q)
            areg[q] = __float2bfloat16(__bfloat162float(areg[q]) + __bfloat162float(breg[q]));
        }
      } else {
#pragma unroll
        for (int q = 0; q < 16; ++q) areg[q] = __float2bfloat16(0.f);
      }
      bf16 wreg[NG][16];
#pragma unroll
      for (int g = 0; g < NG; ++g) {
        const int wr = n0 + srow;
        if (wr < p.Nc) {
          const bf16* wp = W + (long)(p.gateOff[g] + wr) * ldw + k0 + scol;
          *(float4*)(wreg[g])     = *(const float4*)(wp);
          *(float4*)(wreg[g] + 8) = *(const float4*)(wp + 8);
        } else {
#pragma unroll
          for (int q = 0; q < 16; ++q) wreg[g][q] = __float2bfloat16(0.f);
        }
      }
      __syncthreads();
      *(float4*)&As[srow][scol]     = *(float4*)(areg);
      *(float4*)&As[srow][scol + 8] = *(float4*)(areg + 8);
#pragma unroll
      for (int g = 0; g < NG; ++g) {
        *(float4*)&Ws[g][srow][scol]     = *(float4*)(wreg[g]);
        *(float4*)&Ws[g][srow][scol + 8] = *(float4*)(wreg[g] + 8);
      }
      __syncthreads();
#pragma unroll
      for (int kc = 0; kc < 2; ++kc) {
        const int ko = kc * 32 + ((lane >> 4) << 3);
        s16x8 bfr[NG];
#pragma unroll
        for (int g = 0; g < NG; ++g)
          bfr[g] = *(const s16x8*)&Ws[g][(wv << 4) + (lane & 15)][ko];
#pragma unroll
        for (int mf = 0; mf < 4; ++mf) {
          s16x8 afr = *(const s16x8*)&As[(mf << 4) + (lane & 15)][ko];
#pragma unroll
          for (int g = 0; g < NG; ++g)
            acc[g][mf] = __builtin_amdgcn_mfma_f32_16x16x32_bf16(afr, bfr[g], acc[g][mf], 0, 0, 0);
        }
      }
    }
  }

  // epilogue — C/D layout: col=lane&15, row=(lane>>4)*4+reg  [m89-verified]
  const int colg = n0 + (wv << 4) + (lane & 15);
  if (colg >= p.Nc) return;
  const float* b0 = p.base0[z]; const int* gx = p.gidx[z];
  const float* b1 = p.base1[z]; const float* b2 = p.base2[z];
  const float* bs = p.bias[z];

  if (MODE == 0) {
    float* C = p.Cf[z];
#pragma unroll
    for (int mf = 0; mf < 4; ++mf)
#pragma unroll
      for (int r = 0; r < 4; ++r) {
        const int row = m0 + (mf << 4) + ((lane >> 4) << 2) + r;
        if (row >= p.M) continue;
#pragma unroll
        for (int g = 0; g < NG; ++g) {
          float v = acc[g][mf][r];
          if (bs) v += bs[p.gateOff[g] + colg];
          C[(long)row * p.ldc + p.gateOff[g] + colg] = v;
        }
      }
  } else if (MODE == 1) {
    bf16* Ch = p.Ch[z];
#pragma unroll
    for (int mf = 0; mf < 4; ++mf)
#pragma unroll
      for (int r = 0; r < 4; ++r) {
        const int row = m0 + (mf << 4) + ((lane >> 4) << 2) + r;
        if (row >= p.M) continue;
        float gi = acc[0][mf][r], gg = acc[1][mf][r], go = acc[2][mf][r];
        if (b0) {
          long r0 = gx ? (long)gx[(long)row * p.gstride] : (long)row;
          const float* q = b0 + r0 * G4_;
          gi += q[p.gateOff[0] + colg]; gg += q[p.gateOff[1] + colg]; go += q[p.gateOff[2] + colg];
        }
        if (b1) { const float* q = b1 + (long)row * G4_;
          gi += q[p.gateOff[0] + colg]; gg += q[p.gateOff[1] + colg]; go += q[p.gateOff[2] + colg]; }
        if (b2) { const float* q = b2 + (long)row * G4_;
          gi += q[p.gateOff[0] + colg]; gg += q[p.gateOff[1] + colg]; go += q[p.gateOff[2] + colg]; }
        if (bs) { gi += bs[p.gateOff[0] + colg]; gg += bs[p.gateOff[1] + colg]; go += bs[p.gateOff[2] + colg]; }
        float h = sigf(go) * tanhfa(sigf(gi) * tanhfa(gg));
        Ch[(long)row * p.ldh + colg] = __float2bfloat16(h);
      }
  } else { // MODE 2: tanh -> bf16, single gate
    bf16* Ch = p.Ch[z];
#pragma unroll
    for (int mf = 0; mf < 4; ++mf)
#pragma unroll
      for (int r = 0; r < 4; ++r) {
        const int row = m0 + (mf << 4) + ((lane >> 4) << 2) + r;
        if (row >= p.M) continue;
        float v = acc[0][mf][r];
        if (bs) v += bs[colg];
        Ch[(long)row * p.ldh + colg] = __float2bfloat16(tanhfa(v));
      }
  }
}

__global__ __launch_bounds__(256) void conv_k(const float* s, bf16* d, long n4) {
  long i = (long)blockIdx.x * 256 + threadIdx.x;
  if (i >= n4) return;
  float4 v = ((const float4*)s)[i];
  d[4 * i]     = __float2bfloat16(v.x);
  d[4 * i + 1] = __float2bfloat16(v.y);
  d[4 * i + 2] = __float2bfloat16(v.z);
  d[4 * i + 3] = __float2bfloat16(v.w);
}

__global__ __launch_bounds__(256) void reset_k(const bf16* Hb, bf16* h1, bf16* h2, bf16* ctx) {
  const long idx = (long)blockIdx.x * 256 + threadIdx.x;  // < B*H
  const bf16 v = Hb[idx];
  h1[idx] = v; h1[idx + BH_] = v; h1[idx + 2L * BH_] = v;
  h2[idx] = v; h2[idx + BH_] = v; h2[idx + 2L * BH_] = v;
  ctx[idx] = v;
}

__global__ __launch_bounds__(256) void x1cat_k(const float* emb, const float* c, int bar, bf16* x1) {
  const long idx = (long)blockIdx.x * 256 + threadIdx.x;  // < 3*B*1024
  const int i = (int)(idx >> 18);
  const int r = (int)(idx & 262143);
  const int b = r >> 10;
  const int k = r & 1023;
  float v;
  if (k < CH_) v = emb[(long)i * V_ * CH_ + k];
  else         v = c[(long)b * BARS_ * CH_ + (long)bar * CH_ + (k - CH_)];
  x1[idx] = __float2bfloat16(v);
}

extern "C" void kernel_launch(void* const* d_in, const int* in_sizes, int n_in,
                              void* d_out, int out_size, void* d_ws, size_t ws_size,
                              hipStream_t stream) {
  const float* c     = (const float*)d_in[0];
  const float* l1Wih = (const float*)d_in[1];
  const float* l1Whh = (const float*)d_in[2];
  const float* l1b   = (const float*)d_in[3];
  const float* cWih  = (const float*)d_in[4];
  const float* cWhh  = (const float*)d_in[5];
  const float* cb    = (const float*)d_in[6];
  const float* l2Wih = (const float*)d_in[7];
  const float* l2Whh = (const float*)d_in[8];
  const float* l2b   = (const float*)d_in[9];
  const float* outW  = (const float*)d_in[10];
  const float* outb  = (const float*)d_in[11];
  const float* hidW  = (const float*)d_in[12];
  const float* hidb  = (const float*)d_in[13];
  const float* emb   = (const float*)d_in[14];
  const int*   target = (const int*)d_in[15];
  float* out = (float*)d_out;

  // ---- workspace carve (~220 MB; all sub-regions 16B-aligned) ----
  char* wp = (char*)d_ws;
  auto cf = [&](long n) { float* r = (float*)wp; wp += n * sizeof(float); return r; };
  auto ch = [&](long n) { bf16*  r = (bf16*)wp;  wp += n * sizeof(bf16);  return r; };
  float* embW = cf(3L * V_ * G4_);
  float* xW1  = cf(3L * BG_);
  float* cW2  = cf(3L * BG_);
  float* cWu  = cf(1L * BG_);
  float* Pb   = cf(3L * BG_);
  float* Pp   = cf(2L * BG_);
  bf16* l1Wih_h = ch(3L * G4_ * 1024);
  bf16* l1Whh_h = ch(3L * G4_ * 1024);
  bf16* cWih_h  = ch((long)G4_ * 3072);
  bf16* cWhh_h  = ch((long)G4_ * 1024);
  bf16* l2Wih_h = ch(3L * G4_ * 1536);
  bf16* l2Whh_h = ch(3L * G4_ * 1024);
  bf16* outW_h  = ch(3L * V_ * 1024);
  bf16* hidW_h  = ch(1024L * 512);
  bf16* emb_h   = ch(3L * V_ * CH_);
  bf16* c_h     = ch((long)B_ * BARS_ * CH_);
  bf16* x1_h    = ch(3L * B_ * 1024);
  bf16* Hbar_h  = ch((long)BH_);
  bf16* h1buf[2] = { ch(3L * BH_), ch(3L * BH_) };
  bf16* h2buf[2] = { ch(3L * BH_), ch(3L * BH_) };
  bf16* ctxbuf[2] = { ch((long)BH_), ch((long)BH_) };
  bf16* unew = ch(2L * BH_);

  auto conv = [&](const float* s, bf16* d, long n) {
    long n4 = n / 4;
    conv_k<<<dim3((unsigned)((n4 + 255) / 256)), dim3(256), 0, stream>>>(s, d, n4);
  };
  conv(l1Wih, l1Wih_h, 3L * G4_ * 1024);
  conv(l1Whh, l1Whh_h, 3L * G4_ * 1024);
  conv(cWih,  cWih_h,  (long)G4_ * 3072);
  conv(cWhh,  cWhh_h,  (long)G4_ * 1024);
  conv(l2Wih, l2Wih_h, 3L * G4_ * 1536);
  conv(l2Whh, l2Whh_h, 3L * G4_ * 1024);
  conv(outW,  outW_h,  3L * V_ * 1024);
  conv(hidW,  hidW_h,  1024L * 512);
  conv(emb,   emb_h,   3L * V_ * CH_);
  conv(c,     c_h,     (long)B_ * BARS_ * CH_);

  const int GOFF[3] = { 0, 2048, 3072 };  // i, g, o (f gate is dead)

  { // embW[i] = emb[i] @ l1Wih[1][:, :512]^T  (once; no bias — folded into cWu)
    MP p{};
    for (int z = 0; z < 3; ++z) {
      p.A0[z] = emb_h + (long)z * V_ * CH_;
      p.W0[z] = l1Wih_h + (long)G4_ * 1024;
      p.Cf[z] = embW + (long)z * V_ * G4_;
    }
    p.lda0 = CH_; p.ldw0 = 1024; p.K0 = CH_;
    p.gateOff[0] = GOFF[0]; p.gateOff[1] = GOFF[1]; p.gateOff[2] = GOFF[2];
    p.M = V_; p.Nc = H_; p.ldc = G4_;
    mfma_gemm<3, 0><<<dim3(16, 3, 3), dim3(256), 0, stream>>>(p);
  }

  for (int t = 0; t < T_; ++t) {
    const int bar = t >> 4;
    const int rb = t & 1, wb = rb ^ 1;
    bf16* h1r = h1buf[rb]; bf16* h1w = h1buf[wb];
    bf16* h2r = h2buf[rb]; bf16* h2w = h2buf[wb];

    if ((t & 15) == 0) {
      const int prev = bar ? bar - 1 : 0;
      { // Hbar = tanh(c[:,prev,:] @ hidW^T + hidb)  -> bf16
        MP p{};
        p.A0[0] = c_h + (long)prev * CH_; p.lda0 = BARS_ * CH_;
        p.W0[0] = hidW_h; p.ldw0 = CH_; p.K0 = CH_;
        p.bias[0] = hidb; p.Ch[0] = Hbar_h;
        p.M = B_; p.Nc = H_; p.ldh = H_;
        mfma_gemm<1, 2><<<dim3(16, 4, 1), dim3(256), 0, stream>>>(p);
      }
      reset_k<<<dim3(BH_ / 256), dim3(256), 0, stream>>>(Hbar_h, h1buf[rb], h2buf[rb], ctxbuf[rb]);
      x1cat_k<<<dim3(3 * BH_ / 256), dim3(256), 0, stream>>>(emb, c, bar, x1_h);
      { // xW1[i] = x1cat[i] @ l1Wih[i]^T + l1b[i]
        MP p{};
        for (int z = 0; z < 3; ++z) {
          p.A0[z] = x1_h + (long)z * B_ * 1024;
          p.W0[z] = l1Wih_h + (long)z * G4_ * 1024;
          p.bias[z] = l1b + (long)z * G4_;
          p.Cf[z] = xW1 + (long)z * BG_;
        }
        p.lda0 = 1024; p.ldw0 = 1024; p.K0 = 1024;
        p.gateOff[0] = GOFF[0]; p.gateOff[1] = GOFF[1]; p.gateOff[2] = GOFF[2];
        p.M = B_; p.Nc = H_; p.ldc = G4_;
        mfma_gemm<3, 0><<<dim3(16, 4, 3), dim3(256), 0, stream>>>(p);
      }
      { // cW2[i] = c_bar @ l2Wih[i][:, 1024:]^T + l2b[i]
        MP p{};
        for (int z = 0; z < 3; ++z) {
          p.A0[z] = c_h + (long)bar * CH_;
          p.W0[z] = l2Wih_h + (long)z * G4_ * 1536 + 1024;
          p.bias[z] = l2b + (long)z * G4_;
          p.Cf[z] = cW2 + (long)z * BG_;
        }
        p.lda0 = BARS_ * CH_; p.ldw0 = 1536; p.K0 = CH_;
        p.gateOff[0] = GOFF[0]; p.gateOff[1] = GOFF[1]; p.gateOff[2] = GOFF[2];
        p.M = B_; p.Nc = H_; p.ldc = G4_;
        mfma_gemm<3, 0><<<dim3(16, 4, 3), dim3(256), 0, stream>>>(p);
      }
      { // cWu = c_bar @ l1Wih[1][:, 512:]^T + l1b[1]
        MP p{};
        p.A0[0] = c_h + (long)bar * CH_; p.lda0 = BARS_ * CH_;
        p.W0[0] = l1Wih_h + (long)G4_ * 1024 + 512; p.ldw0 = 1024; p.K0 = CH_;
        p.bias[0] = l1b + G4_; p.Cf[0] = cWu;
        p.gateOff[0] = GOFF[0]; p.gateOff[1] = GOFF[1]; p.gateOff[2] = GOFF[2];
        p.M = B_; p.Nc = H_; p.ldc = G4_;
        mfma_gemm<3, 0><<<dim3(16, 4, 1), dim3(256), 0, stream>>>(p);
      }
    }

    { // h1[i] = lstm_act( h1r[i] @ l1Whh[i]^T + xW1[i] )  -> h1w
      MP p{};
      for (int z = 0; z < 3; ++z) {
        p.A0[z] = h1r + (long)z * BH_;
        p.W0[z] = l1Whh_h + (long)z * G4_ * 1024;
        p.base0[z] = xW1 + (long)z * BG_;
        p.Ch[z] = h1w + (long)z * BH_;
      }
      p.lda0 = H_; p.ldw0 = H_; p.K0 = H_;
      p.gateOff[0] = GOFF[0]; p.gateOff[1] = GOFF[1]; p.gateOff[2] = GOFF[2];
      p.M = B_; p.Nc = H_; p.ldh = H_;
      mfma_gemm<3, 1><<<dim3(16, 4, 3), dim3(256), 0, stream>>>(p);
    }
    { // unew[i] = lstm_act( h1w[i] @ l1Whh[1]^T + embW[i][tg] + cWu ),  i=0,1 (i=2 dead)
      MP p{};
      for (int z = 0; z < 2; ++z) {
        p.A0[z] = h1w + (long)z * BH_;
        p.W0[z] = l1Whh_h + (long)G4_ * 1024;
        p.base0[z] = embW + (long)z * V_ * G4_;
        p.gidx[z] = target + (long)z * B_ * T_ + t;
        p.base1[z] = cWu;
        p.Ch[z] = unew + (long)z * BH_;
      }
      p.lda0 = H_; p.ldw0 = H_; p.K0 = H_; p.gstride = T_;
      p.gateOff[0] = GOFF[0]; p.gateOff[1] = GOFF[1]; p.gateOff[2] = GOFF[2];
      p.M = B_; p.Nc = H_; p.ldh = H_;
      mfma_gemm<3, 1><<<dim3(16, 4, 2), dim3(256), 0, stream>>>(p);
    }
    { // P partials: {h1w0,h1w1,h1w2,u0*,u1*} @ ctx_Wih[:, j*1024:]^T
      MP p{};
      const bf16* As5[5] = { h1w, h1w + BH_, h1w + 2L * BH_, unew, unew + BH_ };
      const int js[5] = { 0, 1, 2, 0, 1 };
      float* Cs[5] = { Pb, Pb + BG_, Pb + 2L * BG_, Pp, Pp + BG_ };
      for (int z = 0; z < 5; ++z) {
        p.A0[z] = As5[z];
        p.W0[z] = cWih_h + (long)js[z] * 1024;
        p.Cf[z] = Cs[z];
      }
      p.lda0 = H_; p.ldw0 = 3072; p.K0 = H_;
      p.gateOff[0] = GOFF[0]; p.gateOff[1] = GOFF[1]; p.gateOff[2] = GOFF[2];
      p.M = B_; p.Nc = H_; p.ldc = G4_;
      mfma_gemm<3, 0><<<dim3(16, 4, 5), dim3(256), 0, stream>>>(p);
    }

    int cc = t & 1;   // ctx ping-pong index (3 flips/step keeps parity = t&1 at step start)
    for (int i = 0; i < 3; ++i) {
      bf16* cr = ctxbuf[cc]; bf16* cw = ctxbuf[cc ^ 1]; cc ^= 1;
      { // ctx = lstm_act( cr @ cWhh^T + P0 + P1 + P2 + cb ) -> cw
        MP p{};
        p.A0[0] = cr; p.lda0 = H_;
        p.W0[0] = cWhh_h; p.ldw0 = H_; p.K0 = H_;
        p.base0[0] = (i >= 1) ? Pp : Pb;
        p.base1[0] = (i >= 2) ? Pp + BG_ : Pb + BG_;
        p.base2[0] = Pb + 2L * BG_;
        p.bias[0] = cb; p.Ch[0] = cw;
        p.gateOff[0] = GOFF[0]; p.gateOff[1] = GOFF[1]; p.gateOff[2] = GOFF[2];
        p.M = B_; p.Nc = H_; p.ldh = H_;
        mfma_gemm<3, 1><<<dim3(16, 4, 1), dim3(256), 0, stream>>>(p);
      }
      { // h2[i] = lstm_act( cw @ l2Wih[i][:, :1024]^T + h2r[i] @ l2Whh[i]^T + cW2[i] ) -> h2w
        MP p{};
        p.A0[0] = cw; p.lda0 = H_;
        p.W0[0] = l2Wih_h + (long)i * G4_ * 1536; p.ldw0 = 1536; p.K0 = H_;
        p.A1[0] = h2r + (long)i * BH_; p.lda1 = H_;
        p.W1[0] = l2Whh_h + (long)i * G4_ * 1024; p.ldw1 = H_; p.K1 = H_;
        p.base0[0] = cW2 + (long)i * BG_;
        p.Ch[0] = h2w + (long)i * BH_;
        p.gateOff[0] = GOFF[0]; p.gateOff[1] = GOFF[1]; p.gateOff[2] = GOFF[2];
        p.M = B_; p.Nc = H_; p.ldh = H_;
        mfma_gemm<3, 1><<<dim3(16, 4, 1), dim3(256), 0, stream>>>(p);
      }
    }
    { // out[i][:, t, :] = (h1w[i] + h2w[i]) @ outW[i]^T + outb[i]
      MP p{};
      for (int z = 0; z < 3; ++z) {
        p.A0[z]  = h1w + (long)z * BH_;
        p.A0b[z] = h2w + (long)z * BH_;
        p.W0[z]  = outW_h + (long)z * V_ * H_;
        p.bias[z] = outb + (long)z * V_;
        p.Cf[z] = out + (long)z * B_ * T_ * V_ + (long)t * V_;
      }
      p.lda0 = H_; p.ldw0 = H_; p.K0 = H_;
      p.gateOff[0] = 0;
      p.M = B_; p.Nc = V_; p.ldc = T_ * V_;
      mfma_gemm<1, 0><<<dim3(3, 4, 3), dim3(256), 0, stream>>>(p);
    }
  }
}